// Round 5
// baseline (21.600 us; speedup 1.0000x reference)
//
#include <hip/hip_runtime.h>
#include <math.h>

// PMSN Vandermonde kernel via factored complex recurrence + packed fp32 math.
// out[h,l] = Re( sum_n w_n * Abar_n^l ),  w = C*B_bar, Abar = exp(dt*A).
// H=2048, N=4, L=8192 -> 64 MiB fp32 output (write floor ~10.6us @6.3TB/s).
//
// One block (256 thr) per h. Thread t at iteration it covers l = 4t+j+1024*it.
// State y[n] = w_n * Abar^(4t+1024*it), advanced by M = Abar^1024.
// Outputs o[j] = Re sum_n y[n]*u[j][n], u[j][n] = Abar^j.
// All packed across n-pairs (n01 / n23) with v_pk_{mul,fma,add}_f32 (VOP3P
// 2-wide fp32 — hipcc never auto-forms these): ~27 VALU instrs per 4 outputs
// vs ~53 scalar. Imag-constants pre-negated so no op_sel modifiers needed.
// Large-l phases via double-precision fract (fp32 fract at ~300 rev loses 2e-4).
// Output via __builtin_nontemporal_store on a clang ext-vector float4
// (HIP_vector_type is rejected by the builtin).

#define HH 2048
#define NN 4
#define LL 8192

typedef float f32x2 __attribute__((ext_vector_type(2)));
typedef float f32x4 __attribute__((ext_vector_type(4)));

static __device__ __forceinline__ f32x2 pk_mul(f32x2 a, f32x2 b) {
    f32x2 d; asm("v_pk_mul_f32 %0, %1, %2" : "=v"(d) : "v"(a), "v"(b)); return d;
}
static __device__ __forceinline__ f32x2 pk_fma(f32x2 a, f32x2 b, f32x2 c) {
    f32x2 d; asm("v_pk_fma_f32 %0, %1, %2, %3" : "=v"(d) : "v"(a), "v"(b), "v"(c)); return d;
}
static __device__ __forceinline__ f32x2 pk_add(f32x2 a, f32x2 b) {
    f32x2 d; asm("v_pk_add_f32 %0, %1, %2" : "=v"(d) : "v"(a), "v"(b)); return d;
}

__global__ __launch_bounds__(256) void pmsn_kernel(
    const float* __restrict__ log_dt,
    const float* __restrict__ log_A_real,
    const float* __restrict__ A_imag,
    const float* __restrict__ VinvB_real,
    const float* __restrict__ VinvB_imag,
    const float* __restrict__ CV_real,
    const float* __restrict__ CV_imag,
    float* __restrict__ out)
{
    __shared__ double s_thr[NN];          // revolutions per step
    __shared__ float  s_a2[NN];           // log2-decay per step
    __shared__ float2 s_w[NN];            // C * B_bar
    __shared__ float2 s_u[3][NN];         // Abar^j, j=1..3
    __shared__ float2 s_M[NN];            // Abar^1024

    const int h   = blockIdx.x;
    const int tid = threadIdx.x;

    if (tid < NN) {
        const int n = tid, idx = h * NN + n;
        const float dt  = __expf(log_dt[h]);
        const float Are = -__expf(log_A_real[idx]);
        const float Aim = A_imag[idx];
        const double dt_d  = (double)dt;
        const double a_d   = dt_d * (double)Are;                  // ln-decay/step
        const double th_d  = dt_d * (double)Aim;                  // rad/step
        const double thr_d = th_d * 0.15915494309189533577;       // rev/step
        const double a2_d  = a_d * 1.4426950408889634074;         // log2/step

        // w = C * B_bar,  B_bar = (Abar - 1) * B / A
        const float er = __expf((float)a_d);
        float sn, cs; __sincosf((float)th_d, &sn, &cs);
        const float Am1r = __fmaf_rn(er, cs, -1.0f);
        const float Am1i = er * sn;
        const float Br = VinvB_real[idx], Bi = VinvB_imag[idx];
        const float numr = Am1r * Br - Am1i * Bi;
        const float numi = Am1r * Bi + Am1i * Br;
        const float invden = 1.0f / (Are * Are + Aim * Aim);
        const float Bbr = (numr * Are + numi * Aim) * invden;
        const float Bbi = (numi * Are - numr * Aim) * invden;
        const float Cr = CV_real[idx], Ci = CV_imag[idx];
        s_w[n] = make_float2(Cr * Bbr - Ci * Bbi, Cr * Bbi + Ci * Bbr);

        s_thr[n] = thr_d;
        s_a2[n]  = (float)a2_d;

        #pragma unroll
        for (int j = 1; j <= 3; ++j) {
            const double t = thr_d * (double)j;
            const float p = (float)(t - floor(t));
            const float e = __builtin_amdgcn_exp2f((float)(a2_d * (double)j));
            s_u[j-1][n] = make_float2(e * __builtin_amdgcn_cosf(p),
                                      e * __builtin_amdgcn_sinf(p));
        }
        {
            const double t = thr_d * 1024.0;
            const float p = (float)(t - floor(t));
            const float e = __builtin_amdgcn_exp2f((float)(a2_d * 1024.0));
            s_M[n] = make_float2(e * __builtin_amdgcn_cosf(p),
                                 e * __builtin_amdgcn_sinf(p));
        }
    }
    __syncthreads();

    // Packed constants across n-pairs (imag parts pre-negated where needed).
    f32x2 Ur01[3], Ur23[3], nUi01[3], nUi23[3];
    #pragma unroll
    for (int j = 0; j < 3; ++j) {
        Ur01[j]  = (f32x2){ s_u[j][0].x,  s_u[j][1].x};
        Ur23[j]  = (f32x2){ s_u[j][2].x,  s_u[j][3].x};
        nUi01[j] = (f32x2){-s_u[j][0].y, -s_u[j][1].y};
        nUi23[j] = (f32x2){-s_u[j][2].y, -s_u[j][3].y};
    }
    const f32x2 Mr01  = (f32x2){ s_M[0].x,  s_M[1].x};
    const f32x2 Mr23  = (f32x2){ s_M[2].x,  s_M[3].x};
    const f32x2 Mi01  = (f32x2){ s_M[0].y,  s_M[1].y};
    const f32x2 Mi23  = (f32x2){ s_M[2].y,  s_M[3].y};
    const f32x2 nMi01 = (f32x2){-s_M[0].y, -s_M[1].y};
    const f32x2 nMi23 = (f32x2){-s_M[2].y, -s_M[3].y};

    // Initialize y[n] = w_n * Abar^l0, then pack.
    const int l0 = tid << 2;
    float yr[NN], yi[NN];
    #pragma unroll
    for (int n = 0; n < NN; ++n) {
        const double ph_d = s_thr[n] * (double)l0;
        const float  p    = (float)(ph_d - floor(ph_d));
        const float  c    = __builtin_amdgcn_cosf(p);
        const float  s    = __builtin_amdgcn_sinf(p);
        const float  env  = __builtin_amdgcn_exp2f(s_a2[n] * (float)l0);
        const float wr = s_w[n].x, wi = s_w[n].y;
        yr[n] = (wr * c - wi * s) * env;
        yi[n] = (wr * s + wi * c) * env;
    }
    f32x2 Yr01 = (f32x2){yr[0], yr[1]}, Yr23 = (f32x2){yr[2], yr[3]};
    f32x2 Yi01 = (f32x2){yi[0], yi[1]}, Yi23 = (f32x2){yi[2], yi[3]};

    float* outp = out + (size_t)h * LL + l0;
    #pragma unroll
    for (int it = 0; it < 8; ++it) {
        f32x4 o;
        {
            f32x2 t = pk_add(Yr01, Yr23);
            o.x = t.x + t.y;
        }
        {
            f32x2 acc = pk_mul(Yi01, nUi01[0]);
            acc = pk_fma(Yr01, Ur01[0], acc);
            acc = pk_fma(Yi23, nUi23[0], acc);
            acc = pk_fma(Yr23, Ur23[0], acc);
            o.y = acc.x + acc.y;
        }
        {
            f32x2 acc = pk_mul(Yi01, nUi01[1]);
            acc = pk_fma(Yr01, Ur01[1], acc);
            acc = pk_fma(Yi23, nUi23[1], acc);
            acc = pk_fma(Yr23, Ur23[1], acc);
            o.z = acc.x + acc.y;
        }
        {
            f32x2 acc = pk_mul(Yi01, nUi01[2]);
            acc = pk_fma(Yr01, Ur01[2], acc);
            acc = pk_fma(Yi23, nUi23[2], acc);
            acc = pk_fma(Yr23, Ur23[2], acc);
            o.w = acc.x + acc.y;
        }
        __builtin_nontemporal_store(o, reinterpret_cast<f32x4*>(outp + it * 1024));
        if (it < 7) {
            f32x2 t0   = pk_mul(Yi01, nMi01);
            f32x2 nr01 = pk_fma(Yr01, Mr01, t0);
            f32x2 t1   = pk_mul(Yi01, Mr01);
            Yi01 = pk_fma(Yr01, Mi01, t1);
            Yr01 = nr01;
            f32x2 t2   = pk_mul(Yi23, nMi23);
            f32x2 nr23 = pk_fma(Yr23, Mr23, t2);
            f32x2 t3   = pk_mul(Yi23, Mr23);
            Yi23 = pk_fma(Yr23, Mi23, t3);
            Yr23 = nr23;
        }
    }
}

extern "C" void kernel_launch(void* const* d_in, const int* in_sizes, int n_in,
                              void* d_out, int out_size, void* d_ws, size_t ws_size,
                              hipStream_t stream) {
    const float* log_dt     = (const float*)d_in[0];
    const float* log_A_real = (const float*)d_in[1];
    const float* A_imag     = (const float*)d_in[2];
    const float* VinvB_real = (const float*)d_in[3];
    const float* VinvB_imag = (const float*)d_in[4];
    const float* CV_real    = (const float*)d_in[5];
    const float* CV_imag    = (const float*)d_in[6];
    float* out = (float*)d_out;

    dim3 grid(HH);      // one block per h
    dim3 block(256);
    pmsn_kernel<<<grid, block, 0, stream>>>(log_dt, log_A_real, A_imag,
        VinvB_real, VinvB_imag, CV_real, CV_imag, out);
}

// Round 6
// 21.360 us; speedup vs baseline: 1.0112x; 1.0112x over previous
//
#include <hip/hip_runtime.h>
#include <math.h>

// PMSN Vandermonde kernel via factored complex recurrence + packed fp32 math.
// out[h,l] = Re( sum_n w_n * Abar_n^l ),  w = C*B_bar, Abar = exp(dt*A).
// H=2048, N=4, L=8192 -> 64 MiB fp32 output (write floor ~10.6us @6.3TB/s).
//
// One block (256 thr) per h. Thread t at iteration it covers l = 4t+j+1024*it.
// State y[n] = w_n * Abar^(4t+1024*it), advanced by M = Abar^1024.
// Outputs o[j] = Re sum_n y[n]*u[j][n], u[j][n] = Abar^j.
// Packed across n-pairs with v_pk_{mul,fma,add}_f32 (VOP3P 2-wide fp32):
// ~26 VALU instrs per 4 outputs vs ~53 scalar.
// ROUND-5 LESSON: __builtin_nontemporal_store cost +4us (bypasses L2
// write-combining; effective write BW ~4.4 TB/s vs 6.3). Regular store here.
// Large-l phases via double-precision fract.

#define HH 2048
#define NN 4
#define LL 8192

typedef float f32x2 __attribute__((ext_vector_type(2)));
typedef float f32x4 __attribute__((ext_vector_type(4)));

static __device__ __forceinline__ f32x2 pk_mul(f32x2 a, f32x2 b) {
    f32x2 d; asm("v_pk_mul_f32 %0, %1, %2" : "=v"(d) : "v"(a), "v"(b)); return d;
}
static __device__ __forceinline__ f32x2 pk_fma(f32x2 a, f32x2 b, f32x2 c) {
    f32x2 d; asm("v_pk_fma_f32 %0, %1, %2, %3" : "=v"(d) : "v"(a), "v"(b), "v"(c)); return d;
}
static __device__ __forceinline__ f32x2 pk_add(f32x2 a, f32x2 b) {
    f32x2 d; asm("v_pk_add_f32 %0, %1, %2" : "=v"(d) : "v"(a), "v"(b)); return d;
}

__global__ __launch_bounds__(256) void pmsn_kernel(
    const float* __restrict__ log_dt,
    const float* __restrict__ log_A_real,
    const float* __restrict__ A_imag,
    const float* __restrict__ VinvB_real,
    const float* __restrict__ VinvB_imag,
    const float* __restrict__ CV_real,
    const float* __restrict__ CV_imag,
    float* __restrict__ out)
{
    __shared__ double s_thr[NN];          // revolutions per step
    __shared__ float  s_a2[NN];           // log2-decay per step
    __shared__ float2 s_w[NN];            // C * B_bar
    __shared__ float2 s_u[3][NN];         // Abar^j, j=1..3
    __shared__ float2 s_M[NN];            // Abar^1024

    const int h   = blockIdx.x;
    const int tid = threadIdx.x;

    if (tid < NN) {
        const int n = tid, idx = h * NN + n;
        const float dt  = __expf(log_dt[h]);
        const float Are = -__expf(log_A_real[idx]);
        const float Aim = A_imag[idx];
        const double dt_d  = (double)dt;
        const double a_d   = dt_d * (double)Are;                  // ln-decay/step
        const double th_d  = dt_d * (double)Aim;                  // rad/step
        const double thr_d = th_d * 0.15915494309189533577;       // rev/step
        const double a2_d  = a_d * 1.4426950408889634074;         // log2/step

        // w = C * B_bar,  B_bar = (Abar - 1) * B / A
        const float er = __expf((float)a_d);
        float sn, cs; __sincosf((float)th_d, &sn, &cs);
        const float Am1r = __fmaf_rn(er, cs, -1.0f);
        const float Am1i = er * sn;
        const float Br = VinvB_real[idx], Bi = VinvB_imag[idx];
        const float numr = Am1r * Br - Am1i * Bi;
        const float numi = Am1r * Bi + Am1i * Br;
        const float invden = 1.0f / (Are * Are + Aim * Aim);
        const float Bbr = (numr * Are + numi * Aim) * invden;
        const float Bbi = (numi * Are - numr * Aim) * invden;
        const float Cr = CV_real[idx], Ci = CV_imag[idx];
        s_w[n] = make_float2(Cr * Bbr - Ci * Bbi, Cr * Bbi + Ci * Bbr);

        s_thr[n] = thr_d;
        s_a2[n]  = (float)a2_d;

        #pragma unroll
        for (int j = 1; j <= 3; ++j) {
            const double t = thr_d * (double)j;
            const float p = (float)(t - floor(t));
            const float e = __builtin_amdgcn_exp2f((float)(a2_d * (double)j));
            s_u[j-1][n] = make_float2(e * __builtin_amdgcn_cosf(p),
                                      e * __builtin_amdgcn_sinf(p));
        }
        {
            const double t = thr_d * 1024.0;
            const float p = (float)(t - floor(t));
            const float e = __builtin_amdgcn_exp2f((float)(a2_d * 1024.0));
            s_M[n] = make_float2(e * __builtin_amdgcn_cosf(p),
                                 e * __builtin_amdgcn_sinf(p));
        }
    }
    __syncthreads();

    // Packed constants across n-pairs (imag parts pre-negated where needed).
    f32x2 Ur01[3], Ur23[3], nUi01[3], nUi23[3];
    #pragma unroll
    for (int j = 0; j < 3; ++j) {
        Ur01[j]  = (f32x2){ s_u[j][0].x,  s_u[j][1].x};
        Ur23[j]  = (f32x2){ s_u[j][2].x,  s_u[j][3].x};
        nUi01[j] = (f32x2){-s_u[j][0].y, -s_u[j][1].y};
        nUi23[j] = (f32x2){-s_u[j][2].y, -s_u[j][3].y};
    }
    const f32x2 Mr01  = (f32x2){ s_M[0].x,  s_M[1].x};
    const f32x2 Mr23  = (f32x2){ s_M[2].x,  s_M[3].x};
    const f32x2 Mi01  = (f32x2){ s_M[0].y,  s_M[1].y};
    const f32x2 Mi23  = (f32x2){ s_M[2].y,  s_M[3].y};
    const f32x2 nMi01 = (f32x2){-s_M[0].y, -s_M[1].y};
    const f32x2 nMi23 = (f32x2){-s_M[2].y, -s_M[3].y};

    // Initialize y[n] = w_n * Abar^l0, then pack.
    const int l0 = tid << 2;
    float yr[NN], yi[NN];
    #pragma unroll
    for (int n = 0; n < NN; ++n) {
        const double ph_d = s_thr[n] * (double)l0;
        const float  p    = (float)(ph_d - floor(ph_d));
        const float  c    = __builtin_amdgcn_cosf(p);
        const float  s    = __builtin_amdgcn_sinf(p);
        const float  env  = __builtin_amdgcn_exp2f(s_a2[n] * (float)l0);
        const float wr = s_w[n].x, wi = s_w[n].y;
        yr[n] = (wr * c - wi * s) * env;
        yi[n] = (wr * s + wi * c) * env;
    }
    f32x2 Yr01 = (f32x2){yr[0], yr[1]}, Yr23 = (f32x2){yr[2], yr[3]};
    f32x2 Yi01 = (f32x2){yi[0], yi[1]}, Yi23 = (f32x2){yi[2], yi[3]};

    float* outp = out + (size_t)h * LL + l0;
    #pragma unroll
    for (int it = 0; it < 8; ++it) {
        f32x4 o;
        {
            f32x2 t = pk_add(Yr01, Yr23);
            o.x = t.x + t.y;
        }
        {
            f32x2 acc = pk_mul(Yi01, nUi01[0]);
            acc = pk_fma(Yr01, Ur01[0], acc);
            acc = pk_fma(Yi23, nUi23[0], acc);
            acc = pk_fma(Yr23, Ur23[0], acc);
            o.y = acc.x + acc.y;
        }
        {
            f32x2 acc = pk_mul(Yi01, nUi01[1]);
            acc = pk_fma(Yr01, Ur01[1], acc);
            acc = pk_fma(Yi23, nUi23[1], acc);
            acc = pk_fma(Yr23, Ur23[1], acc);
            o.z = acc.x + acc.y;
        }
        {
            f32x2 acc = pk_mul(Yi01, nUi01[2]);
            acc = pk_fma(Yr01, Ur01[2], acc);
            acc = pk_fma(Yi23, nUi23[2], acc);
            acc = pk_fma(Yr23, Ur23[2], acc);
            o.w = acc.x + acc.y;
        }
        *reinterpret_cast<f32x4*>(outp + it * 1024) = o;   // regular store (through L2)
        if (it < 7) {
            f32x2 t0   = pk_mul(Yi01, nMi01);
            f32x2 nr01 = pk_fma(Yr01, Mr01, t0);
            f32x2 t1   = pk_mul(Yi01, Mr01);
            Yi01 = pk_fma(Yr01, Mi01, t1);
            Yr01 = nr01;
            f32x2 t2   = pk_mul(Yi23, nMi23);
            f32x2 nr23 = pk_fma(Yr23, Mr23, t2);
            f32x2 t3   = pk_mul(Yi23, Mr23);
            Yi23 = pk_fma(Yr23, Mi23, t3);
            Yr23 = nr23;
        }
    }
}

extern "C" void kernel_launch(void* const* d_in, const int* in_sizes, int n_in,
                              void* d_out, int out_size, void* d_ws, size_t ws_size,
                              hipStream_t stream) {
    const float* log_dt     = (const float*)d_in[0];
    const float* log_A_real = (const float*)d_in[1];
    const float* A_imag     = (const float*)d_in[2];
    const float* VinvB_real = (const float*)d_in[3];
    const float* VinvB_imag = (const float*)d_in[4];
    const float* CV_real    = (const float*)d_in[5];
    const float* CV_imag    = (const float*)d_in[6];
    float* out = (float*)d_out;

    dim3 grid(HH);      // one block per h
    dim3 block(256);
    pmsn_kernel<<<grid, block, 0, stream>>>(log_dt, log_A_real, A_imag,
        VinvB_real, VinvB_imag, CV_real, CV_imag, out);
}

// Round 7
// 17.700 us; speedup vs baseline: 1.2203x; 1.2068x over previous
//
#include <hip/hip_runtime.h>
#include <math.h>

// PMSN Vandermonde kernel via factored complex recurrence (scalar fp32).
// out[h,l] = Re( sum_n w_n * Abar_n^l ),  w = C*B_bar, Abar = exp(dt*A).
// H=2048, N=4, L=8192 -> 64 MiB fp32 output (write floor ~10.6us @6.3TB/s).
//
// One block (256 thr) per h. Thread t at iteration it covers l = 4t+j+1024*it.
// State: y[n] = w_n * Abar^(4t+1024*it)   (4 complex regs, advanced by
// M = Abar^1024, 16 ops/iter).  Outputs: o[j] = Re sum_n y[n]*u[j][n] with
// u[j][n] = Abar^j wave-uniform constants held in SGPRs via readfirstlane.
// ~11 lane-ops/output, all plain scalar FMAs the compiler schedules freely.
//
// Tried and REVERTED (keep for the record):
//  - v_pk_{fma,mul,add}_f32 inline asm (round 5/6): +4us. gfx950 fp32 spec
//    157.3TF is WITHOUT packing -> pk is throughput-neutral, and 26 opaque
//    asm blocks/iter defeat the compiler scheduler.
//  - __builtin_nontemporal_store (round 5): +0.2us, no benefit.
// Large-l phases via double-precision fract (fp32 fract at ~300 rev loses 2e-4).

#define HH 2048
#define NN 4
#define LL 8192

__device__ __forceinline__ float rfl(float x) {
    return __int_as_float(__builtin_amdgcn_readfirstlane(__float_as_int(x)));
}

__global__ __launch_bounds__(256) void pmsn_kernel(
    const float* __restrict__ log_dt,
    const float* __restrict__ log_A_real,
    const float* __restrict__ A_imag,
    const float* __restrict__ VinvB_real,
    const float* __restrict__ VinvB_imag,
    const float* __restrict__ CV_real,
    const float* __restrict__ CV_imag,
    float* __restrict__ out)
{
    __shared__ double s_thr[NN];          // revolutions per step
    __shared__ float  s_a2[NN];           // log2-decay per step
    __shared__ float2 s_w[NN];            // C * B_bar
    __shared__ float2 s_u[3][NN];         // Abar^j, j=1..3
    __shared__ float2 s_M[NN];            // Abar^1024

    const int h   = blockIdx.x;
    const int tid = threadIdx.x;

    if (tid < NN) {
        const int n = tid, idx = h * NN + n;
        const float dt  = __expf(log_dt[h]);
        const float Are = -__expf(log_A_real[idx]);
        const float Aim = A_imag[idx];
        const double dt_d  = (double)dt;
        const double a_d   = dt_d * (double)Are;                  // ln-decay/step
        const double th_d  = dt_d * (double)Aim;                  // rad/step
        const double thr_d = th_d * 0.15915494309189533577;       // rev/step
        const double a2_d  = a_d * 1.4426950408889634074;         // log2/step

        // w = C * B_bar,  B_bar = (Abar - 1) * B / A
        const float er = __expf((float)a_d);
        float sn, cs; __sincosf((float)th_d, &sn, &cs);
        const float Am1r = __fmaf_rn(er, cs, -1.0f);
        const float Am1i = er * sn;
        const float Br = VinvB_real[idx], Bi = VinvB_imag[idx];
        const float numr = Am1r * Br - Am1i * Bi;
        const float numi = Am1r * Bi + Am1i * Br;
        const float invden = 1.0f / (Are * Are + Aim * Aim);
        const float Bbr = (numr * Are + numi * Aim) * invden;
        const float Bbi = (numi * Are - numr * Aim) * invden;
        const float Cr = CV_real[idx], Ci = CV_imag[idx];
        s_w[n] = make_float2(Cr * Bbr - Ci * Bbi, Cr * Bbi + Ci * Bbr);

        s_thr[n] = thr_d;
        s_a2[n]  = (float)a2_d;

        // u_j = Abar^j, j = 1..3 (computed directly for accuracy)
        #pragma unroll
        for (int j = 1; j <= 3; ++j) {
            const double t = thr_d * (double)j;
            const float p = (float)(t - floor(t));
            const float e = __builtin_amdgcn_exp2f((float)(a2_d * (double)j));
            s_u[j-1][n] = make_float2(e * __builtin_amdgcn_cosf(p),
                                      e * __builtin_amdgcn_sinf(p));
        }
        // M = Abar^1024 (phase via double fract)
        {
            const double t = thr_d * 1024.0;
            const float p = (float)(t - floor(t));
            const float e = __builtin_amdgcn_exp2f((float)(a2_d * 1024.0));
            s_M[n] = make_float2(e * __builtin_amdgcn_cosf(p),
                                 e * __builtin_amdgcn_sinf(p));
        }
    }
    __syncthreads();

    // Broadcast wave-uniform constants into SGPRs.
    float ur[3][NN], ui[3][NN], Mr[NN], Mi[NN];
    #pragma unroll
    for (int n = 0; n < NN; ++n) {
        #pragma unroll
        for (int j = 0; j < 3; ++j) {
            ur[j][n] = rfl(s_u[j][n].x);
            ui[j][n] = rfl(s_u[j][n].y);
        }
        Mr[n] = rfl(s_M[n].x);
        Mi[n] = rfl(s_M[n].y);
    }

    // Initialize y[n] = w_n * Abar^l0
    const int l0 = tid << 2;
    float yr[NN], yi[NN];
    #pragma unroll
    for (int n = 0; n < NN; ++n) {
        const double ph_d = s_thr[n] * (double)l0;
        const float  p    = (float)(ph_d - floor(ph_d));
        const float  c    = __builtin_amdgcn_cosf(p);
        const float  s    = __builtin_amdgcn_sinf(p);
        const float  env  = __builtin_amdgcn_exp2f(s_a2[n] * (float)l0);
        const float wr = s_w[n].x, wi = s_w[n].y;
        yr[n] = (wr * c - wi * s) * env;
        yi[n] = (wr * s + wi * c) * env;
    }

    float* outp = out + (size_t)h * LL + l0;
    #pragma unroll
    for (int it = 0; it < 8; ++it) {
        float4 o;
        o.x = (yr[0] + yr[1]) + (yr[2] + yr[3]);
        {
            float s0 = yr[0] * ur[0][0] - yi[0] * ui[0][0];
            float s1 = yr[1] * ur[0][1] - yi[1] * ui[0][1];
            float s2 = yr[2] * ur[0][2] - yi[2] * ui[0][2];
            float s3 = yr[3] * ur[0][3] - yi[3] * ui[0][3];
            o.y = (s0 + s1) + (s2 + s3);
        }
        {
            float s0 = yr[0] * ur[1][0] - yi[0] * ui[1][0];
            float s1 = yr[1] * ur[1][1] - yi[1] * ui[1][1];
            float s2 = yr[2] * ur[1][2] - yi[2] * ui[1][2];
            float s3 = yr[3] * ur[1][3] - yi[3] * ui[1][3];
            o.z = (s0 + s1) + (s2 + s3);
        }
        {
            float s0 = yr[0] * ur[2][0] - yi[0] * ui[2][0];
            float s1 = yr[1] * ur[2][1] - yi[1] * ui[2][1];
            float s2 = yr[2] * ur[2][2] - yi[2] * ui[2][2];
            float s3 = yr[3] * ur[2][3] - yi[3] * ui[2][3];
            o.w = (s0 + s1) + (s2 + s3);
        }
        *reinterpret_cast<float4*>(outp + it * 1024) = o;
        if (it < 7) {
            #pragma unroll
            for (int n = 0; n < NN; ++n) {
                const float r = yr[n] * Mr[n] - yi[n] * Mi[n];
                const float i = yr[n] * Mi[n] + yi[n] * Mr[n];
                yr[n] = r; yi[n] = i;
            }
        }
    }
}

extern "C" void kernel_launch(void* const* d_in, const int* in_sizes, int n_in,
                              void* d_out, int out_size, void* d_ws, size_t ws_size,
                              hipStream_t stream) {
    const float* log_dt     = (const float*)d_in[0];
    const float* log_A_real = (const float*)d_in[1];
    const float* A_imag     = (const float*)d_in[2];
    const float* VinvB_real = (const float*)d_in[3];
    const float* VinvB_imag = (const float*)d_in[4];
    const float* CV_real    = (const float*)d_in[5];
    const float* CV_imag    = (const float*)d_in[6];
    float* out = (float*)d_out;

    dim3 grid(HH);      // one block per h
    dim3 block(256);
    pmsn_kernel<<<grid, block, 0, stream>>>(log_dt, log_A_real, A_imag,
        VinvB_real, VinvB_imag, CV_real, CV_imag, out);
}

// Round 8
// 16.852 us; speedup vs baseline: 1.2817x; 1.0503x over previous
//
#include <hip/hip_runtime.h>
#include <math.h>

// PMSN Vandermonde kernel via factored complex recurrence (scalar fp32)
// + wave-uniform decay cutoff.
// out[h,l] = Re( sum_n w_n * Abar_n^l ),  w = C*B_bar, Abar = exp(dt*A).
// H=2048, N=4, L=8192 -> 64 MiB fp32 output (write floor ~10.6us @6.3TB/s).
//
// One block (256 thr) per h. Thread t at iteration it covers l = 4t+j+1024*it.
// State: y[n] = w_n * Abar^(4t+1024*it), advanced by M = Abar^1024.
// Outputs: o[j] = Re sum_n y[n]*u[j][n], u[j][n]=Abar^j in SGPRs (readfirstlane).
//
// DECAY CUTOFF (round 8): envelope 4*Rmax*exp2(a2*l) < 1e-5 (abs threshold is
// 2.3e-3) -> store exact zeros past l_cut. dt log-uniform [1e-3,0.1]: ~56% of
// (h,l) cells are dead (dt=0.1 rows die at l~210). Cutoff is made WAVE-uniform
// (first-lane l0 + readfirstlane) so skipped iterations are scalar-branched
// (s_cbranch) and actually elide VALU issue -- per-lane exec masking would
// save nothing since masked VALU instrs still issue.
//
// Tried and REVERTED: v_pk_* inline asm (+4us: fp32 rate is NOT doubled by
// packing on gfx950, and opaque asm defeats the scheduler); nontemporal
// stores (+0.2us). Large-l phases via double-precision fract.

#define HH 2048
#define NN 4
#define LL 8192

__device__ __forceinline__ float rfl(float x) {
    return __int_as_float(__builtin_amdgcn_readfirstlane(__float_as_int(x)));
}

__global__ __launch_bounds__(256) void pmsn_kernel(
    const float* __restrict__ log_dt,
    const float* __restrict__ log_A_real,
    const float* __restrict__ A_imag,
    const float* __restrict__ VinvB_real,
    const float* __restrict__ VinvB_imag,
    const float* __restrict__ CV_real,
    const float* __restrict__ CV_imag,
    float* __restrict__ out)
{
    __shared__ double s_thr[NN];          // revolutions per step
    __shared__ float  s_a2[NN];           // log2-decay per step
    __shared__ float2 s_w[NN];            // C * B_bar
    __shared__ float2 s_u[3][NN];         // Abar^j, j=1..3
    __shared__ float2 s_M[NN];            // Abar^1024

    const int h   = blockIdx.x;
    const int tid = threadIdx.x;

    if (tid < NN) {
        const int n = tid, idx = h * NN + n;
        const float dt  = __expf(log_dt[h]);
        const float Are = -__expf(log_A_real[idx]);
        const float Aim = A_imag[idx];
        const double dt_d  = (double)dt;
        const double a_d   = dt_d * (double)Are;                  // ln-decay/step
        const double th_d  = dt_d * (double)Aim;                  // rad/step
        const double thr_d = th_d * 0.15915494309189533577;       // rev/step
        const double a2_d  = a_d * 1.4426950408889634074;         // log2/step

        // w = C * B_bar,  B_bar = (Abar - 1) * B / A
        const float er = __expf((float)a_d);
        float sn, cs; __sincosf((float)th_d, &sn, &cs);
        const float Am1r = __fmaf_rn(er, cs, -1.0f);
        const float Am1i = er * sn;
        const float Br = VinvB_real[idx], Bi = VinvB_imag[idx];
        const float numr = Am1r * Br - Am1i * Bi;
        const float numi = Am1r * Bi + Am1i * Br;
        const float invden = 1.0f / (Are * Are + Aim * Aim);
        const float Bbr = (numr * Are + numi * Aim) * invden;
        const float Bbi = (numi * Are - numr * Aim) * invden;
        const float Cr = CV_real[idx], Ci = CV_imag[idx];
        s_w[n] = make_float2(Cr * Bbr - Ci * Bbi, Cr * Bbi + Ci * Bbr);

        s_thr[n] = thr_d;
        s_a2[n]  = (float)a2_d;

        #pragma unroll
        for (int j = 1; j <= 3; ++j) {
            const double t = thr_d * (double)j;
            const float p = (float)(t - floor(t));
            const float e = __builtin_amdgcn_exp2f((float)(a2_d * (double)j));
            s_u[j-1][n] = make_float2(e * __builtin_amdgcn_cosf(p),
                                      e * __builtin_amdgcn_sinf(p));
        }
        {
            const double t = thr_d * 1024.0;
            const float p = (float)(t - floor(t));
            const float e = __builtin_amdgcn_exp2f((float)(a2_d * 1024.0));
            s_M[n] = make_float2(e * __builtin_amdgcn_cosf(p),
                                 e * __builtin_amdgcn_sinf(p));
        }
    }
    __syncthreads();

    // Wave-uniform cutoff iteration count: beyond it, 4*Rmax*exp2(a2*l) < 1e-5.
    float R2max = 0.0f, a2max = -1e30f;
    #pragma unroll
    for (int n = 0; n < NN; ++n) {
        const float wr = s_w[n].x, wi = s_w[n].y;
        R2max = fmaxf(R2max, __fmaf_rn(wr, wr, wi * wi));
        a2max = fmaxf(a2max, s_a2[n]);
    }
    const float Rmax = sqrtf(fmaxf(R2max, 1e-30f));
    // tol/4 = 2.5e-6;  a2max < 0 always (A_real = -exp(..) < 0, dt > 0)
    const float lcut = __log2f(2.5e-6f / Rmax) / a2max;
    const int l0    = tid << 2;
    const int l0min = (tid & ~63) << 2;   // wave's first lane -> max itcut in wave
    int itcut = (int)ceilf((lcut - (float)l0min) * (1.0f / 1024.0f));
    itcut = max(0, min(8, itcut));
    itcut = __builtin_amdgcn_readfirstlane(itcut);   // force SGPR -> scalar branches

    float* outp = out + (size_t)h * LL + l0;
    const float4 zero4 = make_float4(0.0f, 0.0f, 0.0f, 0.0f);

    if (itcut == 0) {
        #pragma unroll
        for (int it = 0; it < 8; ++it)
            *reinterpret_cast<float4*>(outp + it * 1024) = zero4;
        return;
    }

    // Broadcast wave-uniform constants into SGPRs.
    float ur[3][NN], ui[3][NN], Mr[NN], Mi[NN];
    #pragma unroll
    for (int n = 0; n < NN; ++n) {
        #pragma unroll
        for (int j = 0; j < 3; ++j) {
            ur[j][n] = rfl(s_u[j][n].x);
            ui[j][n] = rfl(s_u[j][n].y);
        }
        Mr[n] = rfl(s_M[n].x);
        Mi[n] = rfl(s_M[n].y);
    }

    // Initialize y[n] = w_n * Abar^l0
    float yr[NN], yi[NN];
    #pragma unroll
    for (int n = 0; n < NN; ++n) {
        const double ph_d = s_thr[n] * (double)l0;
        const float  p    = (float)(ph_d - floor(ph_d));
        const float  c    = __builtin_amdgcn_cosf(p);
        const float  s    = __builtin_amdgcn_sinf(p);
        const float  env  = __builtin_amdgcn_exp2f(s_a2[n] * (float)l0);
        const float wr = s_w[n].x, wi = s_w[n].y;
        yr[n] = (wr * c - wi * s) * env;
        yi[n] = (wr * s + wi * c) * env;
    }

    #pragma unroll
    for (int it = 0; it < 8; ++it) {
        if (it < itcut) {
            float4 o;
            o.x = (yr[0] + yr[1]) + (yr[2] + yr[3]);
            {
                float s0 = yr[0] * ur[0][0] - yi[0] * ui[0][0];
                float s1 = yr[1] * ur[0][1] - yi[1] * ui[0][1];
                float s2 = yr[2] * ur[0][2] - yi[2] * ui[0][2];
                float s3 = yr[3] * ur[0][3] - yi[3] * ui[0][3];
                o.y = (s0 + s1) + (s2 + s3);
            }
            {
                float s0 = yr[0] * ur[1][0] - yi[0] * ui[1][0];
                float s1 = yr[1] * ur[1][1] - yi[1] * ui[1][1];
                float s2 = yr[2] * ur[1][2] - yi[2] * ui[1][2];
                float s3 = yr[3] * ur[1][3] - yi[3] * ui[1][3];
                o.z = (s0 + s1) + (s2 + s3);
            }
            {
                float s0 = yr[0] * ur[2][0] - yi[0] * ui[2][0];
                float s1 = yr[1] * ur[2][1] - yi[1] * ui[2][1];
                float s2 = yr[2] * ur[2][2] - yi[2] * ui[2][2];
                float s3 = yr[3] * ur[2][3] - yi[3] * ui[2][3];
                o.w = (s0 + s1) + (s2 + s3);
            }
            *reinterpret_cast<float4*>(outp + it * 1024) = o;
            if (it < 7) {
                #pragma unroll
                for (int n = 0; n < NN; ++n) {
                    const float r = yr[n] * Mr[n] - yi[n] * Mi[n];
                    const float i = yr[n] * Mi[n] + yi[n] * Mr[n];
                    yr[n] = r; yi[n] = i;
                }
            }
        } else {
            *reinterpret_cast<float4*>(outp + it * 1024) = zero4;
        }
    }
}

extern "C" void kernel_launch(void* const* d_in, const int* in_sizes, int n_in,
                              void* d_out, int out_size, void* d_ws, size_t ws_size,
                              hipStream_t stream) {
    const float* log_dt     = (const float*)d_in[0];
    const float* log_A_real = (const float*)d_in[1];
    const float* A_imag     = (const float*)d_in[2];
    const float* VinvB_real = (const float*)d_in[3];
    const float* VinvB_imag = (const float*)d_in[4];
    const float* CV_real    = (const float*)d_in[5];
    const float* CV_imag    = (const float*)d_in[6];
    float* out = (float*)d_out;

    dim3 grid(HH);      // one block per h
    dim3 block(256);
    pmsn_kernel<<<grid, block, 0, stream>>>(log_dt, log_A_real, A_imag,
        VinvB_real, VinvB_imag, CV_real, CV_imag, out);
}

// Round 9
// 16.762 us; speedup vs baseline: 1.2886x; 1.0054x over previous
//
#include <hip/hip_runtime.h>
#include <math.h>

// PMSN Vandermonde kernel: factored complex recurrence (scalar fp32)
// + wave-uniform decay cutoff + CONJUGATE-PAIR MODE MERGE.
// out[h,l] = Re( sum_n w_n * Abar_n^l ) = 2*Re( sum_{n: Im>0} w_n Abar_n^l )
// because S = -0.5I + K (K real skew-symmetric) makes modes conjugate pairs
// with conjugate weights (real system => real kernel). Runtime compaction by
// sign(A_imag) (no reliance on eigh ordering); 2x folded into the weight.
// 2 live modes instead of 4: ~21 VALU ops / 4 outputs (was 43).
//
// H=2048, N=4, L=8192 -> 64 MiB fp32 output (write floor ~10.6us @6.3TB/s).
// One block (256 thr) per h; thread t covers l = 4t+j+1024*it, it=0..7.
// State y[m] advanced by M = Abar^1024; outputs via u_j = Abar^j in SGPRs.
// DECAY CUTOFF: past env < tol, store exact zeros (wave-uniform, scalar-branched).
// Tried and REVERTED: v_pk_* asm (+4us), nontemporal stores (+0.2us).
// Large-l phases via double-precision fract.

#define HH 2048
#define NN 4     // raw modes
#define NM 2     // live (positive-imag) modes
#define LL 8192

__device__ __forceinline__ float rfl(float x) {
    return __int_as_float(__builtin_amdgcn_readfirstlane(__float_as_int(x)));
}

__global__ __launch_bounds__(256) void pmsn_kernel(
    const float* __restrict__ log_dt,
    const float* __restrict__ log_A_real,
    const float* __restrict__ A_imag,
    const float* __restrict__ VinvB_real,
    const float* __restrict__ VinvB_imag,
    const float* __restrict__ CV_real,
    const float* __restrict__ CV_imag,
    float* __restrict__ out)
{
    // raw per-mode data (phase A), then compacted live modes (phase B)
    __shared__ double s_rthr[NN];
    __shared__ float  s_ra2[NN];
    __shared__ float2 s_rw[NN], s_ru[3][NN], s_rM[NN];
    __shared__ int    s_pos[NN];

    __shared__ double s_thr[NM];
    __shared__ float  s_a2[NM];
    __shared__ float2 s_w[NM], s_u[3][NM], s_M[NM];

    const int h   = blockIdx.x;
    const int tid = threadIdx.x;

    if (tid < NN) {
        const int n = tid, idx = h * NN + n;
        const float dt  = __expf(log_dt[h]);
        const float Are = -__expf(log_A_real[idx]);
        const float Aim = A_imag[idx];
        const double dt_d  = (double)dt;
        const double a_d   = dt_d * (double)Are;                  // ln-decay/step
        const double th_d  = dt_d * (double)Aim;                  // rad/step
        const double thr_d = th_d * 0.15915494309189533577;       // rev/step
        const double a2_d  = a_d * 1.4426950408889634074;         // log2/step

        // w = C * B_bar,  B_bar = (Abar - 1) * B / A
        const float er = __expf((float)a_d);
        float sn, cs; __sincosf((float)th_d, &sn, &cs);
        const float Am1r = __fmaf_rn(er, cs, -1.0f);
        const float Am1i = er * sn;
        const float Br = VinvB_real[idx], Bi = VinvB_imag[idx];
        const float numr = Am1r * Br - Am1i * Bi;
        const float numi = Am1r * Bi + Am1i * Br;
        const float invden = 1.0f / (Are * Are + Aim * Aim);
        const float Bbr = (numr * Are + numi * Aim) * invden;
        const float Bbi = (numi * Are - numr * Aim) * invden;
        const float Cr = CV_real[idx], Ci = CV_imag[idx];
        s_rw[n] = make_float2(Cr * Bbr - Ci * Bbi, Cr * Bbi + Ci * Bbr);

        s_rthr[n] = thr_d;
        s_ra2[n]  = (float)a2_d;
        s_pos[n]  = (Aim > 0.0f) ? 1 : 0;

        #pragma unroll
        for (int j = 1; j <= 3; ++j) {
            const double t = thr_d * (double)j;
            const float p = (float)(t - floor(t));
            const float e = __builtin_amdgcn_exp2f((float)(a2_d * (double)j));
            s_ru[j-1][n] = make_float2(e * __builtin_amdgcn_cosf(p),
                                       e * __builtin_amdgcn_sinf(p));
        }
        {
            const double t = thr_d * 1024.0;
            const float p = (float)(t - floor(t));
            const float e = __builtin_amdgcn_exp2f((float)(a2_d * 1024.0));
            s_rM[n] = make_float2(e * __builtin_amdgcn_cosf(p),
                                  e * __builtin_amdgcn_sinf(p));
        }
    }
    __syncthreads();

    // Phase B: compact positive-imag modes into slots 0..NM-1, weight *= 2.
    if (tid < NN && s_pos[tid]) {
        int slot = 0;
        #pragma unroll
        for (int m = 0; m < NN; ++m) if (m < tid) slot += s_pos[m];
        if (slot < NM) {
            s_thr[slot] = s_rthr[tid];
            s_a2[slot]  = s_ra2[tid];
            s_w[slot]   = make_float2(2.0f * s_rw[tid].x, 2.0f * s_rw[tid].y);
            #pragma unroll
            for (int j = 0; j < 3; ++j) s_u[j][slot] = s_ru[j][tid];
            s_M[slot]   = s_rM[tid];
        }
    }
    __syncthreads();

    // Wave-uniform cutoff: beyond it, NM*Rmax*exp2(a2*l) < 1e-5 (thr 2.3e-3).
    float R2max = 0.0f, a2max = -1e30f;
    #pragma unroll
    for (int m = 0; m < NM; ++m) {
        const float wr = s_w[m].x, wi = s_w[m].y;
        R2max = fmaxf(R2max, __fmaf_rn(wr, wr, wi * wi));
        a2max = fmaxf(a2max, s_a2[m]);
    }
    const float Rmax = sqrtf(fmaxf(R2max, 1e-30f));
    const float lcut = __log2f(5.0e-6f / Rmax) / a2max;   // tol/NM = 5e-6
    const int l0    = tid << 2;
    const int l0min = (tid & ~63) << 2;   // wave's first lane
    int itcut = (int)ceilf((lcut - (float)l0min) * (1.0f / 1024.0f));
    itcut = max(0, min(8, itcut));
    itcut = __builtin_amdgcn_readfirstlane(itcut);   // SGPR -> scalar branches

    float* outp = out + (size_t)h * LL + l0;
    const float4 zero4 = make_float4(0.0f, 0.0f, 0.0f, 0.0f);

    if (itcut == 0) {
        #pragma unroll
        for (int it = 0; it < 8; ++it)
            *reinterpret_cast<float4*>(outp + it * 1024) = zero4;
        return;
    }

    // Broadcast wave-uniform constants into SGPRs (imag pre-negated for fma).
    float ur[3][NM], nui[3][NM], Mr[NM], Mi[NM];
    #pragma unroll
    for (int m = 0; m < NM; ++m) {
        #pragma unroll
        for (int j = 0; j < 3; ++j) {
            ur[j][m]  = rfl(s_u[j][m].x);
            nui[j][m] = rfl(-s_u[j][m].y);
        }
        Mr[m] = rfl(s_M[m].x);
        Mi[m] = rfl(s_M[m].y);
    }

    // Initialize y[m] = w_m * Abar^l0
    float yr[NM], yi[NM];
    #pragma unroll
    for (int m = 0; m < NM; ++m) {
        const double ph_d = s_thr[m] * (double)l0;
        const float  p    = (float)(ph_d - floor(ph_d));
        const float  c    = __builtin_amdgcn_cosf(p);
        const float  s    = __builtin_amdgcn_sinf(p);
        const float  env  = __builtin_amdgcn_exp2f(s_a2[m] * (float)l0);
        const float wr = s_w[m].x, wi = s_w[m].y;
        yr[m] = (wr * c - wi * s) * env;
        yi[m] = (wr * s + wi * c) * env;
    }

    #pragma unroll
    for (int it = 0; it < 8; ++it) {
        if (it < itcut) {
            float4 o;
            o.x = yr[0] + yr[1];
            {
                float s = yr[0] * ur[0][0];
                s = __fmaf_rn(yi[0], nui[0][0], s);
                s = __fmaf_rn(yr[1], ur[0][1], s);
                s = __fmaf_rn(yi[1], nui[0][1], s);
                o.y = s;
            }
            {
                float s = yr[0] * ur[1][0];
                s = __fmaf_rn(yi[0], nui[1][0], s);
                s = __fmaf_rn(yr[1], ur[1][1], s);
                s = __fmaf_rn(yi[1], nui[1][1], s);
                o.z = s;
            }
            {
                float s = yr[0] * ur[2][0];
                s = __fmaf_rn(yi[0], nui[2][0], s);
                s = __fmaf_rn(yr[1], ur[2][1], s);
                s = __fmaf_rn(yi[1], nui[2][1], s);
                o.w = s;
            }
            *reinterpret_cast<float4*>(outp + it * 1024) = o;
            if (it < 7) {
                #pragma unroll
                for (int m = 0; m < NM; ++m) {
                    const float r = yr[m] * Mr[m] - yi[m] * Mi[m];
                    const float i = yr[m] * Mi[m] + yi[m] * Mr[m];
                    yr[m] = r; yi[m] = i;
                }
            }
        } else {
            *reinterpret_cast<float4*>(outp + it * 1024) = zero4;
        }
    }
}

extern "C" void kernel_launch(void* const* d_in, const int* in_sizes, int n_in,
                              void* d_out, int out_size, void* d_ws, size_t ws_size,
                              hipStream_t stream) {
    const float* log_dt     = (const float*)d_in[0];
    const float* log_A_real = (const float*)d_in[1];
    const float* A_imag     = (const float*)d_in[2];
    const float* VinvB_real = (const float*)d_in[3];
    const float* VinvB_imag = (const float*)d_in[4];
    const float* CV_real    = (const float*)d_in[5];
    const float* CV_imag    = (const float*)d_in[6];
    float* out = (float*)d_out;

    dim3 grid(HH);      // one block per h
    dim3 block(256);
    pmsn_kernel<<<grid, block, 0, stream>>>(log_dt, log_A_real, A_imag,
        VinvB_real, VinvB_imag, CV_real, CV_imag, out);
}